// Round 9
// baseline (473.332 us; speedup 1.0000x reference)
//
#include <hip/hip_runtime.h>

// SGC: out = A^K (x w) + b, A = D^-1/2 (Adj+I) D^-1/2, K=2, on per-node scalars y = x.w.
// Evidence log:
//  R1/R2: per-edge device atomics ~16.7G/s -> 48us/pass (k_deg too). Dead.
//  R2 ledger: inter-kernel boundary ~0.2us -> multi-kernel fine. R6: grid.sync path 285us. Dead.
//  R7 (best, 57.7us): 7 dispatches. R8: 4 dispatches = 62.5us -> fixed-dispatch-cost model DEAD;
//  time is inside kernels, models off >5x for something. Inputs are L3-resident across replays,
//  so steady state is latency-bound, not HBM-bound.
//  R9 (THIS ROUND = DIAGNOSTIC): R7 structure with REP=16 inside every kernel (idempotent reps,
//  asm memory clobber blocks dead-store elision). Slowest kernel type will surface above the
//  40us harness-poison fills in top-5; its true time = shown/16. dur_us expected ~16x57.7.

#define REP       16

#define CHUNK_LG  10
#define CHUNK     1024
#define NCHMAX    64
#define TILEA     8192
#define CAPR      256       // slots per (tile,chunk) run
#define NS        8         // hop slabs per chunk

// ---------- K1: blocks [0,nbin) bin one 8192-edge tile; blocks [nbin,..) compute y = x.w ----------
__global__ __launch_bounds__(256)
void ka_bin_dot(const float* __restrict__ x, const int* __restrict__ src,
                const int* __restrict__ dst, const float* __restrict__ W,
                int n, int E, int nbin,
                unsigned* __restrict__ binned, int* __restrict__ bcnt,
                float* __restrict__ y)
{
    __shared__ unsigned raw[TILEA];                    // 32 KB
    __shared__ int hist[NCHMAX], base_[NCHMAX], cur[NCHMAX];
    const int t = threadIdx.x, bid = blockIdx.x;

    if (bid < nbin) {
        for (int rep = 0; rep < REP; ++rep) {
            if (t < NCHMAX) hist[t] = 0;
            __syncthreads();
            const int e0 = bid * TILEA;
            int nrec = E - e0; if (nrec > TILEA) nrec = TILEA;
            #pragma unroll
            for (int k = 0; k < TILEA / 256; k++) {
                int j = k * 256 + t;
                if (j < nrec) {
                    int s = src[e0 + j], d = dst[e0 + j];
                    int ch = d >> CHUNK_LG;
                    raw[j] = ((unsigned)ch << 26) | ((unsigned)(d & (CHUNK - 1)) << 16) | (unsigned)s;
                    atomicAdd(&hist[ch], 1);
                }
            }
            __syncthreads();
            if (t < 64) {                              // wave-0 scan over 64 buckets
                int h = hist[t], v = h;
                #pragma unroll
                for (int off = 1; off < 64; off <<= 1) {
                    int w = __shfl_up(v, off);
                    if (t >= off) v += w;
                }
                base_[t] = v - h; cur[t] = v - h;
                bcnt[bid * NCHMAX + t] = (h > CAPR) ? CAPR : h;
            }
            __syncthreads();
            #pragma unroll
            for (int k = 0; k < TILEA / 256; k++) {
                int j = k * 256 + t;
                if (j < nrec) {
                    unsigned r = raw[j];
                    int ch  = r >> 26;
                    int pos = atomicAdd(&cur[ch], 1) - base_[ch];
                    if (pos < CAPR)
                        binned[(((size_t)(bid * NCHMAX + ch)) << 8) + pos] = r & 0x03FFFFFFu;
                }
            }
            __syncthreads();                           // protect hist/cur reinit next rep
            asm volatile("" ::: "memory");
        }
    } else {
        const int lane = t & 63;
        const float2 wv = ((const float2*)W)[lane];
        for (int rep = 0; rep < REP; ++rep) {
            int i = (bid - nbin) * 4 + (t >> 6);       // one wave per node
            if (i < n) {
                float2 xv = ((const float2*)(x + (size_t)i * 128))[lane];
                float v = xv.x * wv.x + xv.y * wv.y;
                #pragma unroll
                for (int off = 32; off; off >>= 1) v += __shfl_xor(v, off);
                if (lane == 0) y[i] = v;
            }
            asm volatile("" ::: "memory");
        }
    }
}

// ---------- hop: block (c,m) accumulates slab m of chunk c in LDS; coalesced partial write ----------
template <int MODE>   // 0: degree (val=1), 1: sum val[src]
__global__ __launch_bounds__(256)
void kb_hop(const unsigned* __restrict__ binned, const int* __restrict__ bcnt,
            int ntiles, const float* __restrict__ val, float* __restrict__ partial)
{
    __shared__ float acc[CHUNK];
    const int c = blockIdx.x >> 3;                     // / NS
    const int m = blockIdx.x & (NS - 1);
    const int t = threadIdx.x;
    for (int rep = 0; rep < REP; ++rep) {
        #pragma unroll
        for (int k = 0; k < CHUNK / 256; k++) acc[t + k * 256] = 0.f;
        __syncthreads();
        for (int b = m; b < ntiles; b += NS) {
            int len = bcnt[b * NCHMAX + c];
            const unsigned* run = binned + (((size_t)(b * NCHMAX + c)) << 8);
            for (int j = t; j < len; j += 256) {
                unsigned r = run[j];
                float v = (MODE == 0) ? 1.0f : val[r & 0xFFFFu];
                atomicAdd(&acc[r >> 16], v);           // ds_add_f32
            }
        }
        __syncthreads();
        float* pp = partial + (((size_t)(c * NS + m)) << CHUNK_LG);
        #pragma unroll
        for (int k = 0; k < CHUNK / 256; k++) pp[t + k * 256] = acc[t + k * 256];
        __syncthreads();                               // protect acc re-zero next rep
        asm volatile("" ::: "memory");
    }
}

// ---------- reduce slabs + epilogue ----------
// V0: dis=rsqrt(deg+1), u=dis*y   V1: u2=dis^2*(s+u)   V2: out=dis*(s+u2)+b
template <int V>
__global__ __launch_bounds__(256)
void kc_red(const float* __restrict__ partial, int n,
            const float* __restrict__ y, float* __restrict__ dis,
            float* __restrict__ u, float* __restrict__ u2,
            const float* __restrict__ bias, float* __restrict__ out)
{
    int c = blockIdx.x;
    for (int rep = 0; rep < REP; ++rep) {
        #pragma unroll
        for (int k = 0; k < CHUNK / 256; k++) {
            int l = k * 256 + threadIdx.x;
            int i = (c << CHUNK_LG) + l;
            if (i >= n) continue;
            const float* pp = partial + (((size_t)(c * NS)) << CHUNK_LG) + l;
            float s = 0.f;
            #pragma unroll
            for (int m = 0; m < NS; m++) s += pp[m << CHUNK_LG];
            if (V == 0) { float d = rsqrtf(s + 1.0f); dis[i] = d; u[i] = d * y[i]; }
            if (V == 1) { float d = dis[i]; u2[i] = d * d * (s + u[i]); }
            if (V == 2) { out[i] = dis[i] * (s + u2[i]) + bias[0]; }
        }
        asm volatile("" ::: "memory");
    }
}

// ---------------- fallback (R5 proven path, non-REP) ----------------
#define NSLAB 16
#define RECS  7

__global__ void k_zero(int* __restrict__ cnt) { cnt[threadIdx.x] = 0; }

__global__ void k_bin(const int* __restrict__ src, const int* __restrict__ dst,
                      int E, int nchunks, int cap,
                      int* __restrict__ cnt, unsigned int* __restrict__ binned) {
    __shared__ int hist[NCHMAX], base[NCHMAX], cur[NCHMAX];
    int t = threadIdx.x;
    if (t < NCHMAX) { hist[t] = 0; cur[t] = 0; }
    __syncthreads();
    int e0 = blockIdx.x * (RECS * 256);
    unsigned int rec[RECS]; int ch[RECS];
    #pragma unroll
    for (int k = 0; k < RECS; k++) {
        int e = e0 + k * 256 + t;
        if (e < E) {
            int s = src[e], d = dst[e];
            ch[k]  = d >> CHUNK_LG;
            rec[k] = ((unsigned)(d & (CHUNK - 1)) << 16) | (unsigned)s;
            atomicAdd(&hist[ch[k]], 1);
        } else ch[k] = -1;
    }
    __syncthreads();
    if (t < nchunks) base[t] = atomicAdd(&cnt[t], hist[t]);
    __syncthreads();
    #pragma unroll
    for (int k = 0; k < RECS; k++) {
        if (ch[k] >= 0) {
            int slot = base[ch[k]] + atomicAdd(&cur[ch[k]], 1);
            if (slot < cap) binned[(size_t)ch[k] * cap + slot] = rec[k];
        }
    }
}

template <int MODE>
__global__ void k_hop(const unsigned int* __restrict__ binned, const int* __restrict__ cnt,
                      int cap, const float* __restrict__ val, float* __restrict__ partial) {
    __shared__ float acc[CHUNK];
    int c = blockIdx.x >> 4;
    int m = blockIdx.x & (NSLAB - 1);
    int t = threadIdx.x;
    #pragma unroll
    for (int k = 0; k < CHUNK / 256; k++) acc[t + k * 256] = 0.f;
    __syncthreads();
    int nc = cnt[c]; if (nc > cap) nc = cap;
    const unsigned int* bb = binned + (size_t)c * cap;
    for (int e = m * 256 + t; e < nc; e += NSLAB * 256) {
        unsigned int r = bb[e];
        float v = (MODE == 0) ? 1.0f : val[r & 0xFFFFu];
        atomicAdd(&acc[r >> 16], v);
    }
    __syncthreads();
    float* pp = partial + ((size_t)(c * NSLAB + m) << CHUNK_LG);
    #pragma unroll
    for (int k = 0; k < CHUNK / 256; k++) pp[t + k * 256] = acc[t + k * 256];
}

__global__ void k_dot(const float* __restrict__ x, const float* __restrict__ W,
                      float* __restrict__ y, int n) {
    int wid  = (blockIdx.x * blockDim.x + threadIdx.x) >> 6;
    int lane = threadIdx.x & 63;
    if (wid >= n) return;
    float2 xv = ((const float2*)(x + (size_t)wid * 128))[lane];
    float2 wv = ((const float2*)W)[lane];
    float v = xv.x * wv.x + xv.y * wv.y;
    #pragma unroll
    for (int off = 32; off; off >>= 1) v += __shfl_xor(v, off);
    if (lane == 0) y[wid] = v;
}

template <int V>
__global__ void k_reduce(const float* __restrict__ partial, int n,
                         const float* __restrict__ y, float* __restrict__ dis,
                         float* __restrict__ u, float* __restrict__ u2,
                         const float* __restrict__ b, float* __restrict__ out) {
    int i = blockIdx.x * blockDim.x + threadIdx.x;
    if (i >= n) return;
    int c = i >> CHUNK_LG, l = i & (CHUNK - 1);
    const float* pp = partial + ((size_t)(c * NSLAB) << CHUNK_LG) + l;
    float s = 0.f;
    #pragma unroll
    for (int m = 0; m < NSLAB; m++) s += pp[m << CHUNK_LG];
    if (V == 0) { float d = rsqrtf(s + 1.0f); dis[i] = d; u[i] = d * y[i]; }
    if (V == 1) { float d = dis[i]; u2[i] = d * d * (s + u[i]); }
    if (V == 2) { out[i] = dis[i] * (s + u2[i]) + b[0]; }
}

extern "C" void kernel_launch(void* const* d_in, const int* in_sizes, int n_in,
                              void* d_out, int out_size, void* d_ws, size_t ws_size,
                              hipStream_t stream) {
    const float* x  = (const float*)d_in[0];
    const int*   ei = (const int*)d_in[1];   // [2,E]; row0=src, row1=dst
    const float* W  = (const float*)d_in[2];
    const float* b  = (const float*)d_in[3];
    float* out = (float*)d_out;

    const int n = out_size;            // 50000
    const int E = in_sizes[1] / 2;     // 800000
    const int D = in_sizes[0] / n;     // 128
    const int* src = ei;
    const int* dst = ei + E;

    const int C      = (n + CHUNK - 1) >> CHUNK_LG;        // 49
    const int ntiles = (E + TILEA - 1) / TILEA;            // 98

    // fast-path ws (words): binned | bcnt | partial | y | dis | u | u2
    size_t w_binned = (size_t)ntiles * NCHMAX * CAPR;
    size_t w_bcnt   = (size_t)ntiles * NCHMAX;
    size_t w_part   = (size_t)C * NS * CHUNK;
    size_t need     = (w_binned + w_bcnt + w_part + 4 * (size_t)n) * 4;

    if (D == 128 && n <= 65536 && C <= NCHMAX && ws_size >= need) {
        unsigned* binned = (unsigned*)d_ws;
        int*      bcnt   = (int*)d_ws + w_binned;
        float*    part   = (float*)d_ws + w_binned + w_bcnt;
        float*    y      = part + w_part;
        float*    dis    = y + n;
        float*    u      = dis + n;
        float*    u2     = u + n;

        const int dotBlocks = (n + 3) / 4;                 // one wave per node
        const int gridA     = ntiles + dotBlocks;
        const int hopBlocks = C * NS;

        ka_bin_dot<<<gridA, 256, 0, stream>>>(x, src, dst, W, n, E, ntiles, binned, bcnt, y);
        kb_hop<0><<<hopBlocks, 256, 0, stream>>>(binned, bcnt, ntiles, y, part);      // degree
        kc_red<0><<<C, 256, 0, stream>>>(part, n, y, dis, u, u2, b, out);
        kb_hop<1><<<hopBlocks, 256, 0, stream>>>(binned, bcnt, ntiles, u, part);      // hop 1
        kc_red<1><<<C, 256, 0, stream>>>(part, n, y, dis, u, u2, b, out);
        kb_hop<1><<<hopBlocks, 256, 0, stream>>>(binned, bcnt, ntiles, u2, part);     // hop 2
        kc_red<2><<<C, 256, 0, stream>>>(part, n, y, dis, u, u2, b, out);
        return;
    }

    // fallback: R5 proven binned multi-kernel path (CHUNK=1024)
    {
        const int TBf = 256;
        const int Cf  = (n + CHUNK - 1) >> CHUNK_LG;
        const int cap = (int)((long long)E * 5 / (4 * Cf)) + 512;
        int*          cnt    = (int*)d_ws;
        unsigned int* binned = (unsigned int*)(cnt + 64);
        float*        part   = (float*)(binned + (size_t)Cf * cap);
        float*        y      = part + (size_t)Cf * NSLAB * CHUNK;
        float*        dis    = y + n;
        float*        u      = dis + n;
        float*        u2     = u + n;

        const int binBlocks = (E + RECS * 256 - 1) / (RECS * 256);
        const int hopBlocks = Cf * NSLAB;
        const int nb        = (n + TBf - 1) / TBf;
        const int dotBlocks = ((size_t)n * 64 + TBf - 1) / TBf;

        k_zero<<<1, 64, 0, stream>>>(cnt);
        k_bin<<<binBlocks, TBf, 0, stream>>>(src, dst, E, Cf, cap, cnt, binned);
        k_dot<<<dotBlocks, TBf, 0, stream>>>(x, W, y, n);
        k_hop<0><<<hopBlocks, TBf, 0, stream>>>(binned, cnt, cap, y, part);
        k_reduce<0><<<nb, TBf, 0, stream>>>(part, n, y, dis, u, u2, b, out);
        k_hop<1><<<hopBlocks, TBf, 0, stream>>>(binned, cnt, cap, u, part);
        k_reduce<1><<<nb, TBf, 0, stream>>>(part, n, y, dis, u, u2, b, out);
        k_hop<1><<<hopBlocks, TBf, 0, stream>>>(binned, cnt, cap, u2, part);
        k_reduce<2><<<nb, TBf, 0, stream>>>(part, n, y, dis, u, u2, b, out);
    }
}

// Round 10
// 75.086 us; speedup vs baseline: 6.3039x; 6.3039x over previous
//
#include <hip/hip_runtime.h>

// SGC: out = A^K (x w) + b, A = D^-1/2 (Adj+I) D^-1/2, K=2, on per-node scalars y = x.w.
// Evidence log:
//  R1/R2: per-edge device-scope atomics ~16.7 G/s -> 48us/pass. Dead.
//  R6: cooperative grid.sync + idle spinners = 285us. Dead.
//  R9 REP=16 diagnostic: warm work ~28-30us total (ka_bin_dot 9.9us, hops ~5us, reds ~1.5us),
//    wall fits  work + ~4us * n_dispatches  across R2/R7/R8/R9 -> small-kernel launch floor.
//  R10: 4 dispatches. Hop kernels fuse slab-reduce+epilogue via last-block-per-chunk:
//    agent-scope partial stores/loads (cross-XCD coherent), per-chunk ticket ACQ_REL.

#define CHUNK_LG  10
#define CHUNK     1024
#define NCHMAX    64
#define TILEA     8192
#define CAPR      256       // slots per (tile,chunk) run; mean 167, +6.9 sigma
#define NS        8         // hop slabs per chunk
#define AGENT     __HIP_MEMORY_SCOPE_AGENT

// ---------- K1: blocks [0,nbin) bin one 8192-edge tile; blocks [nbin,..) y = x.w; zero tickets ----------
__global__ __launch_bounds__(256)
void ka_bin_dot(const float* __restrict__ x, const int* __restrict__ src,
                const int* __restrict__ dst, const float* __restrict__ W,
                int n, int E, int nbin,
                unsigned* __restrict__ binned, int* __restrict__ bcnt,
                float* __restrict__ y, int* __restrict__ ticket)
{
    __shared__ unsigned raw[TILEA];                    // 32 KB
    __shared__ int hist[NCHMAX], base_[NCHMAX], cur[NCHMAX];
    const int t = threadIdx.x, bid = blockIdx.x;

    if (bid < nbin) {
        if (t < NCHMAX) hist[t] = 0;
        __syncthreads();
        const int e0 = bid * TILEA;
        int nrec = E - e0; if (nrec > TILEA) nrec = TILEA;
        #pragma unroll
        for (int k = 0; k < TILEA / 256; k++) {
            int j = k * 256 + t;
            if (j < nrec) {
                int s = src[e0 + j], d = dst[e0 + j];
                int ch = d >> CHUNK_LG;
                raw[j] = ((unsigned)ch << 26) | ((unsigned)(d & (CHUNK - 1)) << 16) | (unsigned)s;
                atomicAdd(&hist[ch], 1);
            }
        }
        __syncthreads();
        if (t < 64) {                                  // wave-0 scan over 64 buckets
            int h = hist[t], v = h;
            #pragma unroll
            for (int off = 1; off < 64; off <<= 1) {
                int w = __shfl_up(v, off);
                if (t >= off) v += w;
            }
            base_[t] = v - h; cur[t] = v - h;
            bcnt[bid * NCHMAX + t] = (h > CAPR) ? CAPR : h;
        }
        __syncthreads();
        #pragma unroll
        for (int k = 0; k < TILEA / 256; k++) {
            int j = k * 256 + t;
            if (j < nrec) {
                unsigned r = raw[j];
                int ch  = r >> 26;
                int pos = atomicAdd(&cur[ch], 1) - base_[ch];
                if (pos < CAPR)
                    binned[(((size_t)(bid * NCHMAX + ch)) << 8) + pos] = r & 0x03FFFFFFu;
            }
        }
    } else {
        if (bid == nbin && t < NCHMAX) ticket[t] = 0;  // zero per-chunk tickets for kh
        const int lane = t & 63;
        const float2 wv = ((const float2*)W)[lane];
        int i = (bid - nbin) * 4 + (t >> 6);           // one wave per node
        if (i < n) {
            float2 xv = ((const float2*)(x + (size_t)i * 128))[lane];
            float v = xv.x * wv.x + xv.y * wv.y;
            #pragma unroll
            for (int off = 32; off; off >>= 1) v += __shfl_xor(v, off);
            if (lane == 0) y[i] = v;
        }
    }
}

// ---------- hop + fused slab-reduce + epilogue (last-block-per-chunk) ----------
// V0: deg -> dis=rsqrt(deg+1), u=dis*y   V1: u2=dis^2*(s+u)   V2: out=dis*(s+u2)+b
template <int V>
__global__ __launch_bounds__(256)
void kh(const unsigned* __restrict__ binned, const int* __restrict__ bcnt,
        int ntiles, int n,
        const float* __restrict__ y, float* __restrict__ dis,
        float* __restrict__ u, float* __restrict__ u2,
        const float* __restrict__ bias, float* __restrict__ out,
        float* __restrict__ partial, int* __restrict__ ticket)
{
    __shared__ float acc[CHUNK];
    __shared__ int s_rank;
    const int c = blockIdx.x >> 3;                     // / NS
    const int m = blockIdx.x & (NS - 1);
    const int t = threadIdx.x;
    #pragma unroll
    for (int k = 0; k < CHUNK / 256; k++) acc[t + k * 256] = 0.f;
    __syncthreads();
    for (int b = m; b < ntiles; b += NS) {
        int len = bcnt[b * NCHMAX + c];
        const unsigned* run = binned + (((size_t)(b * NCHMAX + c)) << 8);
        for (int j = t; j < len; j += 256) {
            unsigned r = run[j];
            float v = (V == 0) ? 1.0f : ((V == 1) ? u[r & 0xFFFFu] : u2[r & 0xFFFFu]);
            atomicAdd(&acc[r >> 16], v);               // ds_add_f32
        }
    }
    __syncthreads();
    // publish slab at agent scope (bypasses non-coherent per-XCD L2)
    float* pp = partial + (((size_t)(c * NS + m)) << CHUNK_LG);
    #pragma unroll
    for (int k = 0; k < CHUNK / 256; k++)
        __hip_atomic_store(&pp[t + k * 256], acc[t + k * 256], __ATOMIC_RELAXED, AGENT);
    __syncthreads();
    if (t == 0)
        s_rank = __hip_atomic_fetch_add(&ticket[c], 1, __ATOMIC_ACQ_REL, AGENT);
    __syncthreads();
    if (s_rank != NS - 1) return;                      // not last block for this chunk

    // last block: reduce NS slabs + epilogue
    const float* pb = partial + (((size_t)(c * NS)) << CHUNK_LG);
    float bb = (V == 2) ? bias[0] : 0.f;
    #pragma unroll
    for (int k = 0; k < CHUNK / 256; k++) {
        int l = t + k * 256;
        int i = (c << CHUNK_LG) + l;
        if (i >= n) continue;
        float s = 0.f;
        #pragma unroll
        for (int mm = 0; mm < NS; mm++)
            s += __hip_atomic_load(&pb[(mm << CHUNK_LG) + l], __ATOMIC_RELAXED, AGENT);
        if (V == 0) { float d = rsqrtf(s + 1.0f); dis[i] = d; u[i] = d * y[i]; }
        if (V == 1) { float d = dis[i]; u2[i] = d * d * (s + u[i]); }
        if (V == 2) { out[i] = dis[i] * (s + u2[i]) + bb; }
    }
    if (t == 0) ticket[c] = 0;                         // reset for next kernel/replay
}

// ---------------- fallback (R5 proven path) ----------------
#define NSLAB 16
#define RECS  7

__global__ void k_zero(int* __restrict__ cnt) { cnt[threadIdx.x] = 0; }

__global__ void k_bin(const int* __restrict__ src, const int* __restrict__ dst,
                      int E, int nchunks, int cap,
                      int* __restrict__ cnt, unsigned int* __restrict__ binned) {
    __shared__ int hist[NCHMAX], base[NCHMAX], cur[NCHMAX];
    int t = threadIdx.x;
    if (t < NCHMAX) { hist[t] = 0; cur[t] = 0; }
    __syncthreads();
    int e0 = blockIdx.x * (RECS * 256);
    unsigned int rec[RECS]; int ch[RECS];
    #pragma unroll
    for (int k = 0; k < RECS; k++) {
        int e = e0 + k * 256 + t;
        if (e < E) {
            int s = src[e], d = dst[e];
            ch[k]  = d >> CHUNK_LG;
            rec[k] = ((unsigned)(d & (CHUNK - 1)) << 16) | (unsigned)s;
            atomicAdd(&hist[ch[k]], 1);
        } else ch[k] = -1;
    }
    __syncthreads();
    if (t < nchunks) base[t] = atomicAdd(&cnt[t], hist[t]);
    __syncthreads();
    #pragma unroll
    for (int k = 0; k < RECS; k++) {
        if (ch[k] >= 0) {
            int slot = base[ch[k]] + atomicAdd(&cur[ch[k]], 1);
            if (slot < cap) binned[(size_t)ch[k] * cap + slot] = rec[k];
        }
    }
}

template <int MODE>
__global__ void k_hop(const unsigned int* __restrict__ binned, const int* __restrict__ cnt,
                      int cap, const float* __restrict__ val, float* __restrict__ partial) {
    __shared__ float acc[CHUNK];
    int c = blockIdx.x >> 4;
    int m = blockIdx.x & (NSLAB - 1);
    int t = threadIdx.x;
    #pragma unroll
    for (int k = 0; k < CHUNK / 256; k++) acc[t + k * 256] = 0.f;
    __syncthreads();
    int nc = cnt[c]; if (nc > cap) nc = cap;
    const unsigned int* bb = binned + (size_t)c * cap;
    for (int e = m * 256 + t; e < nc; e += NSLAB * 256) {
        unsigned int r = bb[e];
        float v = (MODE == 0) ? 1.0f : val[r & 0xFFFFu];
        atomicAdd(&acc[r >> 16], v);
    }
    __syncthreads();
    float* pp = partial + ((size_t)(c * NSLAB + m) << CHUNK_LG);
    #pragma unroll
    for (int k = 0; k < CHUNK / 256; k++) pp[t + k * 256] = acc[t + k * 256];
}

__global__ void k_dot(const float* __restrict__ x, const float* __restrict__ W,
                      float* __restrict__ y, int n) {
    int wid  = (blockIdx.x * blockDim.x + threadIdx.x) >> 6;
    int lane = threadIdx.x & 63;
    if (wid >= n) return;
    float2 xv = ((const float2*)(x + (size_t)wid * 128))[lane];
    float2 wv = ((const float2*)W)[lane];
    float v = xv.x * wv.x + xv.y * wv.y;
    #pragma unroll
    for (int off = 32; off; off >>= 1) v += __shfl_xor(v, off);
    if (lane == 0) y[wid] = v;
}

template <int V>
__global__ void k_reduce(const float* __restrict__ partial, int n,
                         const float* __restrict__ y, float* __restrict__ dis,
                         float* __restrict__ u, float* __restrict__ u2,
                         const float* __restrict__ b, float* __restrict__ out) {
    int i = blockIdx.x * blockDim.x + threadIdx.x;
    if (i >= n) return;
    int c = i >> CHUNK_LG, l = i & (CHUNK - 1);
    const float* pp = partial + ((size_t)(c * NSLAB) << CHUNK_LG) + l;
    float s = 0.f;
    #pragma unroll
    for (int m = 0; m < NSLAB; m++) s += pp[m << CHUNK_LG];
    if (V == 0) { float d = rsqrtf(s + 1.0f); dis[i] = d; u[i] = d * y[i]; }
    if (V == 1) { float d = dis[i]; u2[i] = d * d * (s + u[i]); }
    if (V == 2) { out[i] = dis[i] * (s + u2[i]) + b[0]; }
}

extern "C" void kernel_launch(void* const* d_in, const int* in_sizes, int n_in,
                              void* d_out, int out_size, void* d_ws, size_t ws_size,
                              hipStream_t stream) {
    const float* x  = (const float*)d_in[0];
    const int*   ei = (const int*)d_in[1];   // [2,E]; row0=src, row1=dst
    const float* W  = (const float*)d_in[2];
    const float* b  = (const float*)d_in[3];
    float* out = (float*)d_out;

    const int n = out_size;            // 50000
    const int E = in_sizes[1] / 2;     // 800000
    const int D = in_sizes[0] / n;     // 128
    const int* src = ei;
    const int* dst = ei + E;

    const int C      = (n + CHUNK - 1) >> CHUNK_LG;        // 49
    const int ntiles = (E + TILEA - 1) / TILEA;            // 98

    // fast-path ws (words): binned | bcnt | partial | ticket[64] | y | dis | u | u2
    size_t w_binned = (size_t)ntiles * NCHMAX * CAPR;
    size_t w_bcnt   = (size_t)ntiles * NCHMAX;
    size_t w_part   = (size_t)C * NS * CHUNK;
    size_t need     = (w_binned + w_bcnt + w_part + 64 + 4 * (size_t)n) * 4;

    if (D == 128 && n <= 65536 && C <= NCHMAX && ws_size >= need) {
        unsigned* binned = (unsigned*)d_ws;
        int*      bcnt   = (int*)d_ws + w_binned;
        float*    part   = (float*)d_ws + w_binned + w_bcnt;
        int*      ticket = (int*)(part + w_part);
        float*    y      = (float*)(ticket + 64);
        float*    dis    = y + n;
        float*    u      = dis + n;
        float*    u2     = u + n;

        const int dotBlocks = (n + 3) / 4;                 // one wave per node
        const int gridA     = ntiles + dotBlocks;
        const int hopBlocks = C * NS;

        ka_bin_dot<<<gridA, 256, 0, stream>>>(x, src, dst, W, n, E, ntiles,
                                              binned, bcnt, y, ticket);
        kh<0><<<hopBlocks, 256, 0, stream>>>(binned, bcnt, ntiles, n, y, dis, u, u2, b, out, part, ticket);
        kh<1><<<hopBlocks, 256, 0, stream>>>(binned, bcnt, ntiles, n, y, dis, u, u2, b, out, part, ticket);
        kh<2><<<hopBlocks, 256, 0, stream>>>(binned, bcnt, ntiles, n, y, dis, u, u2, b, out, part, ticket);
        return;
    }

    // fallback: R5 proven binned multi-kernel path (CHUNK=1024)
    {
        const int TBf = 256;
        const int Cf  = (n + CHUNK - 1) >> CHUNK_LG;
        const int cap = (int)((long long)E * 5 / (4 * Cf)) + 512;
        int*          cnt    = (int*)d_ws;
        unsigned int* binned = (unsigned int*)(cnt + 64);
        float*        part   = (float*)(binned + (size_t)Cf * cap);
        float*        y      = part + (size_t)Cf * NSLAB * CHUNK;
        float*        dis    = y + n;
        float*        u      = dis + n;
        float*        u2     = u + n;

        const int binBlocks = (E + RECS * 256 - 1) / (RECS * 256);
        const int hopBlocks = Cf * NSLAB;
        const int nb        = (n + TBf - 1) / TBf;
        const int dotBlocks = ((size_t)n * 64 + TBf - 1) / TBf;

        k_zero<<<1, 64, 0, stream>>>(cnt);
        k_bin<<<binBlocks, TBf, 0, stream>>>(src, dst, E, Cf, cap, cnt, binned);
        k_dot<<<dotBlocks, TBf, 0, stream>>>(x, W, y, n);
        k_hop<0><<<hopBlocks, TBf, 0, stream>>>(binned, cnt, cap, y, part);
        k_reduce<0><<<nb, TBf, 0, stream>>>(part, n, y, dis, u, u2, b, out);
        k_hop<1><<<hopBlocks, TBf, 0, stream>>>(binned, cnt, cap, u, part);
        k_reduce<1><<<nb, TBf, 0, stream>>>(part, n, y, dis, u, u2, b, out);
        k_hop<1><<<hopBlocks, TBf, 0, stream>>>(binned, cnt, cap, u2, part);
        k_reduce<2><<<nb, TBf, 0, stream>>>(part, n, y, dis, u, u2, b, out);
    }
}

// Round 11
// 66.989 us; speedup vs baseline: 7.0659x; 1.1209x over previous
//
#include <hip/hip_runtime.h>

// SGC: out = A^K (x w) + b, A = D^-1/2 (Adj+I) D^-1/2, K=2, on per-node scalars y = x.w.
// Evidence log:
//  R1/R2: per-edge device-scope atomics ~16.7 G/s -> 48us/pass. Dead.
//  R6: cooperative grid.sync + idle blocks = 285us. Dead.
//  R9 REP diag: ka_bin_dot 9.9us (2.59M LDS bank conflicts = contended hist/cur atomics),
//    hops ~5us, reds ~1.5us warm; wall fits work + (launch OR cold-cache) per dispatch.
//  R10: last-block fusion w/ agent-scope tickets+stores = 75us. Cross-XCD coherence ops dead.
//  R11: keep 7-dispatch skeleton; make kernels cheaper:
//    - K1 bin: ONE pass, ballot-match dedup of LDS atomics (64 lanes -> ~50 groups),
//      direct scattered binned writes (R5: write pattern irrelevant), bcnt from cur.
//    - binned/bcnt transposed to [chunk][tile]; hops preload run lengths in one
//      coalesced read -> no serial dependent bcnt stalls.

#define CHUNK_LG  10
#define CHUNK     1024
#define NCHMAX    64
#define TILEA     8192
#define CAPR      256       // slots per (chunk,tile) run; mean 167, +6.9 sigma
#define NS        8         // hop slabs per chunk
#define MAXTPS    16        // max tiles per slab (NT <= 128)

// group lanes of a wave by 6-bit key; returns member mask (valid lanes only)
__device__ __forceinline__ unsigned long long match_ch(int ch, bool valid) {
    unsigned long long m = __ballot(valid);
    #pragma unroll
    for (int bit = 0; bit < 6; ++bit) {
        unsigned long long bm = __ballot(((unsigned)ch >> bit) & 1);
        m &= (((unsigned)ch >> bit) & 1) ? bm : ~bm;
    }
    return m;
}

// ---------- K1: blocks [0,nbin) bin one 8192-edge tile (1 pass); rest: y = x.w ----------
__global__ __launch_bounds__(256)
void ka_bin_dot(const float* __restrict__ x, const int* __restrict__ src,
                const int* __restrict__ dst, const float* __restrict__ W,
                int n, int E, int nbin, int NT,
                unsigned* __restrict__ binned, int* __restrict__ bcnt,
                float* __restrict__ y)
{
    const int t = threadIdx.x, bid = blockIdx.x;

    if (bid < nbin) {
        __shared__ int cur[NCHMAX];
        if (t < NCHMAX) cur[t] = 0;
        __syncthreads();
        const int e0 = bid * TILEA;
        const int nrec = min(E - e0, TILEA);
        const int lane = t & 63;
        const unsigned long long lowmask = (1ull << lane) - 1ull;
        #pragma unroll
        for (int k = 0; k < TILEA / 256; k++) {
            int j = k * 256 + t;
            bool valid = j < nrec;
            int ch = 0; unsigned rec = 0;
            if (valid) {
                int s = src[e0 + j], d = dst[e0 + j];
                ch  = d >> CHUNK_LG;
                rec = ((unsigned)(d & (CHUNK - 1)) << 16) | (unsigned)s;
            }
            unsigned long long mm = match_ch(ch, valid);
            int rank = __popcll(mm & lowmask);
            int base0 = 0;
            if (valid && rank == 0)
                base0 = atomicAdd(&cur[ch], __popcll(mm));      // one LDS atomic per group
            int ldr = __ffsll(mm) - 1;
            base0 = __shfl(base0, ldr >= 0 ? ldr : 0);
            int pos = base0 + rank;
            if (valid && pos < CAPR)
                binned[((size_t)ch * NT + bid) * CAPR + pos] = rec;
        }
        __syncthreads();
        if (t < NCHMAX) bcnt[t * NT + bid] = min(cur[t], CAPR);  // transposed [chunk][tile]
    } else {
        const int lane = t & 63;
        const float2 wv = ((const float2*)W)[lane];
        int i = (bid - nbin) * 4 + (t >> 6);                     // one wave per node
        if (i < n) {
            float2 xv = ((const float2*)(x + (size_t)i * 128))[lane];
            float v = xv.x * wv.x + xv.y * wv.y;
            #pragma unroll
            for (int off = 32; off; off >>= 1) v += __shfl_xor(v, off);
            if (lane == 0) y[i] = v;
        }
    }
}

// ---------- hop: block (c,m) accumulates slab m of chunk c; lens preloaded ----------
template <int MODE>   // 0: degree (val=1), 1: sum val[src]
__global__ __launch_bounds__(256)
void kb_hop(const unsigned* __restrict__ binned, const int* __restrict__ bcnt,
            int NT, const float* __restrict__ val, float* __restrict__ partial)
{
    __shared__ float acc[CHUNK];
    __shared__ int lens[MAXTPS];
    const int c = blockIdx.x >> 3;                      // / NS
    const int m = blockIdx.x & (NS - 1);
    const int t = threadIdx.x;
    #pragma unroll
    for (int k = 0; k < CHUNK / 256; k++) acc[t + k * 256] = 0.f;
    if (t < MAXTPS) {
        int b = m + NS * t;
        lens[t] = (b < NT) ? bcnt[c * NT + b] : 0;      // one coalesced preload, no stalls
    }
    __syncthreads();
    #pragma unroll 1
    for (int i = 0; i < MAXTPS; i++) {
        int len = lens[i];
        if (len == 0) continue;
        const unsigned* run = binned + ((size_t)c * NT + (m + NS * i)) * CAPR;
        for (int j = t; j < len; j += 256) {
            unsigned r = run[j];
            float v = (MODE == 0) ? 1.0f : val[r & 0xFFFFu];
            atomicAdd(&acc[r >> 16], v);                // ds_add_f32
        }
    }
    __syncthreads();
    float* pp = partial + (((size_t)(c * NS + m)) << CHUNK_LG);
    #pragma unroll
    for (int k = 0; k < CHUNK / 256; k++) pp[t + k * 256] = acc[t + k * 256];
}

// ---------- reduce slabs + epilogue ----------
// V0: dis=rsqrt(deg+1), u=dis*y   V1: u2=dis^2*(s+u)   V2: out=dis*(s+u2)+b
template <int V>
__global__ __launch_bounds__(256)
void kc_red(const float* __restrict__ partial, int n,
            const float* __restrict__ y, float* __restrict__ dis,
            float* __restrict__ u, float* __restrict__ u2,
            const float* __restrict__ bias, float* __restrict__ out)
{
    int c = blockIdx.x;
    #pragma unroll
    for (int k = 0; k < CHUNK / 256; k++) {
        int l = k * 256 + threadIdx.x;
        int i = (c << CHUNK_LG) + l;
        if (i >= n) continue;
        const float* pp = partial + (((size_t)(c * NS)) << CHUNK_LG) + l;
        float s = 0.f;
        #pragma unroll
        for (int m = 0; m < NS; m++) s += pp[m << CHUNK_LG];
        if (V == 0) { float d = rsqrtf(s + 1.0f); dis[i] = d; u[i] = d * y[i]; }
        if (V == 1) { float d = dis[i]; u2[i] = d * d * (s + u[i]); }
        if (V == 2) { out[i] = dis[i] * (s + u2[i]) + bias[0]; }
    }
}

// ---------------- fallback (R5 proven path) ----------------
#define NSLAB 16
#define RECS  7

__global__ void k_zero(int* __restrict__ cnt) { cnt[threadIdx.x] = 0; }

__global__ void k_bin(const int* __restrict__ src, const int* __restrict__ dst,
                      int E, int nchunks, int cap,
                      int* __restrict__ cnt, unsigned int* __restrict__ binned) {
    __shared__ int hist[NCHMAX], base[NCHMAX], cur[NCHMAX];
    int t = threadIdx.x;
    if (t < NCHMAX) { hist[t] = 0; cur[t] = 0; }
    __syncthreads();
    int e0 = blockIdx.x * (RECS * 256);
    unsigned int rec[RECS]; int ch[RECS];
    #pragma unroll
    for (int k = 0; k < RECS; k++) {
        int e = e0 + k * 256 + t;
        if (e < E) {
            int s = src[e], d = dst[e];
            ch[k]  = d >> CHUNK_LG;
            rec[k] = ((unsigned)(d & (CHUNK - 1)) << 16) | (unsigned)s;
            atomicAdd(&hist[ch[k]], 1);
        } else ch[k] = -1;
    }
    __syncthreads();
    if (t < nchunks) base[t] = atomicAdd(&cnt[t], hist[t]);
    __syncthreads();
    #pragma unroll
    for (int k = 0; k < RECS; k++) {
        if (ch[k] >= 0) {
            int slot = base[ch[k]] + atomicAdd(&cur[ch[k]], 1);
            if (slot < cap) binned[(size_t)ch[k] * cap + slot] = rec[k];
        }
    }
}

template <int MODE>
__global__ void k_hop(const unsigned int* __restrict__ binned, const int* __restrict__ cnt,
                      int cap, const float* __restrict__ val, float* __restrict__ partial) {
    __shared__ float acc[CHUNK];
    int c = blockIdx.x >> 4;
    int m = blockIdx.x & (NSLAB - 1);
    int t = threadIdx.x;
    #pragma unroll
    for (int k = 0; k < CHUNK / 256; k++) acc[t + k * 256] = 0.f;
    __syncthreads();
    int nc = cnt[c]; if (nc > cap) nc = cap;
    const unsigned int* bb = binned + (size_t)c * cap;
    for (int e = m * 256 + t; e < nc; e += NSLAB * 256) {
        unsigned int r = bb[e];
        float v = (MODE == 0) ? 1.0f : val[r & 0xFFFFu];
        atomicAdd(&acc[r >> 16], v);
    }
    __syncthreads();
    float* pp = partial + ((size_t)(c * NSLAB + m) << CHUNK_LG);
    #pragma unroll
    for (int k = 0; k < CHUNK / 256; k++) pp[t + k * 256] = acc[t + k * 256];
}

__global__ void k_dot(const float* __restrict__ x, const float* __restrict__ W,
                      float* __restrict__ y, int n) {
    int wid  = (blockIdx.x * blockDim.x + threadIdx.x) >> 6;
    int lane = threadIdx.x & 63;
    if (wid >= n) return;
    float2 xv = ((const float2*)(x + (size_t)wid * 128))[lane];
    float2 wv = ((const float2*)W)[lane];
    float v = xv.x * wv.x + xv.y * wv.y;
    #pragma unroll
    for (int off = 32; off; off >>= 1) v += __shfl_xor(v, off);
    if (lane == 0) y[wid] = v;
}

template <int V>
__global__ void k_reduce(const float* __restrict__ partial, int n,
                         const float* __restrict__ y, float* __restrict__ dis,
                         float* __restrict__ u, float* __restrict__ u2,
                         const float* __restrict__ b, float* __restrict__ out) {
    int i = blockIdx.x * blockDim.x + threadIdx.x;
    if (i >= n) return;
    int c = i >> CHUNK_LG, l = i & (CHUNK - 1);
    const float* pp = partial + ((size_t)(c * NSLAB) << CHUNK_LG) + l;
    float s = 0.f;
    #pragma unroll
    for (int m = 0; m < NSLAB; m++) s += pp[m << CHUNK_LG];
    if (V == 0) { float d = rsqrtf(s + 1.0f); dis[i] = d; u[i] = d * y[i]; }
    if (V == 1) { float d = dis[i]; u2[i] = d * d * (s + u[i]); }
    if (V == 2) { out[i] = dis[i] * (s + u2[i]) + b[0]; }
}

extern "C" void kernel_launch(void* const* d_in, const int* in_sizes, int n_in,
                              void* d_out, int out_size, void* d_ws, size_t ws_size,
                              hipStream_t stream) {
    const float* x  = (const float*)d_in[0];
    const int*   ei = (const int*)d_in[1];   // [2,E]; row0=src, row1=dst
    const float* W  = (const float*)d_in[2];
    const float* b  = (const float*)d_in[3];
    float* out = (float*)d_out;

    const int n = out_size;            // 50000
    const int E = in_sizes[1] / 2;     // 800000
    const int D = in_sizes[0] / n;     // 128
    const int* src = ei;
    const int* dst = ei + E;

    const int C  = (n + CHUNK - 1) >> CHUNK_LG;            // 49
    const int NT = (E + TILEA - 1) / TILEA;                // 98

    // fast-path ws (words): binned[C*NT*CAPR] | bcnt[C*NT] | partial[C*NS*CHUNK] | y|dis|u|u2
    size_t w_binned = (size_t)C * NT * CAPR;
    size_t w_bcnt   = (size_t)C * NT;
    size_t w_part   = (size_t)C * NS * CHUNK;
    size_t need     = (w_binned + w_bcnt + w_part + 4 * (size_t)n) * 4;

    if (D == 128 && n <= 65536 && C <= NCHMAX && NT <= NS * MAXTPS && ws_size >= need) {
        unsigned* binned = (unsigned*)d_ws;
        int*      bcnt   = (int*)d_ws + w_binned;
        float*    part   = (float*)d_ws + w_binned + w_bcnt;
        float*    y      = part + w_part;
        float*    dis    = y + n;
        float*    u      = dis + n;
        float*    u2     = u + n;

        const int dotBlocks = (n + 3) / 4;                 // one wave per node
        const int gridA     = NT + dotBlocks;
        const int hopBlocks = C * NS;

        ka_bin_dot<<<gridA, 256, 0, stream>>>(x, src, dst, W, n, E, NT, NT, binned, bcnt, y);
        kb_hop<0><<<hopBlocks, 256, 0, stream>>>(binned, bcnt, NT, y, part);      // degree
        kc_red<0><<<C, 256, 0, stream>>>(part, n, y, dis, u, u2, b, out);
        kb_hop<1><<<hopBlocks, 256, 0, stream>>>(binned, bcnt, NT, u, part);      // hop 1
        kc_red<1><<<C, 256, 0, stream>>>(part, n, y, dis, u, u2, b, out);
        kb_hop<1><<<hopBlocks, 256, 0, stream>>>(binned, bcnt, NT, u2, part);     // hop 2
        kc_red<2><<<C, 256, 0, stream>>>(part, n, y, dis, u, u2, b, out);
        return;
    }

    // fallback: R5 proven binned multi-kernel path (CHUNK=1024)
    {
        const int TBf = 256;
        const int Cf  = (n + CHUNK - 1) >> CHUNK_LG;
        const int cap = (int)((long long)E * 5 / (4 * Cf)) + 512;
        int*          cnt    = (int*)d_ws;
        unsigned int* binned = (unsigned int*)(cnt + 64);
        float*        part   = (float*)(binned + (size_t)Cf * cap);
        float*        y      = part + (size_t)Cf * NSLAB * CHUNK;
        float*        dis    = y + n;
        float*        u      = dis + n;
        float*        u2     = u + n;

        const int binBlocks = (E + RECS * 256 - 1) / (RECS * 256);
        const int hopBlocks = Cf * NSLAB;
        const int nb        = (n + TBf - 1) / TBf;
        const int dotBlocks = ((size_t)n * 64 + TBf - 1) / TBf;

        k_zero<<<1, 64, 0, stream>>>(cnt);
        k_bin<<<binBlocks, TBf, 0, stream>>>(src, dst, E, Cf, cap, cnt, binned);
        k_dot<<<dotBlocks, TBf, 0, stream>>>(x, W, y, n);
        k_hop<0><<<hopBlocks, TBf, 0, stream>>>(binned, cnt, cap, y, part);
        k_reduce<0><<<nb, TBf, 0, stream>>>(part, n, y, dis, u, u2, b, out);
        k_hop<1><<<hopBlocks, TBf, 0, stream>>>(binned, cnt, cap, u, part);
        k_reduce<1><<<nb, TBf, 0, stream>>>(part, n, y, dis, u, u2, b, out);
        k_hop<1><<<hopBlocks, TBf, 0, stream>>>(binned, cnt, cap, u2, part);
        k_reduce<2><<<nb, TBf, 0, stream>>>(part, n, y, dis, u, u2, b, out);
    }
}